// Round 17
// baseline (172.807 us; speedup 1.0000x reference)
//
#include <hip/hip_runtime.h>
#include <math.h>

#define HD 128
#define CHUNK 2048   // edges per binning block
#define MAXBINS 512
#define NPB 128      // nodes per bin
#define CAP 3072     // per-bin capacity (mean 2176, +19 sigma)

typedef __attribute__((ext_vector_type(8))) short bf16x8;
typedef __attribute__((ext_vector_type(4))) float f32x4;
typedef __attribute__((ext_vector_type(2))) float f32x2;

// RNE float -> bf16
__device__ __forceinline__ unsigned short f2bf(float f) {
    unsigned int u = __float_as_uint(f);
    u += 0x7FFFu + ((u >> 16) & 1u);
    return (unsigned short)(u >> 16);
}
// packed bf16 pair -> f32x2
__device__ __forceinline__ f32x2 bfpair(unsigned int p) {
    f32x2 r;
    r.x = __uint_as_float(p << 16);
    r.y = __uint_as_float(p & 0xFFFF0000u);
    return r;
}

// ---------------- W prep: fragment-ordered bf16 B operands (+ cursor init) ----------------
__global__ __launch_bounds__(256) void wprep_kernel(
    const float* __restrict__ W0, const float* __restrict__ W1,
    const float* __restrict__ W2, const float* __restrict__ W3,
    uint4* __restrict__ T0, uint4* __restrict__ T1,
    uint4* __restrict__ T2, uint4* __restrict__ T3,
    int* __restrict__ binCursor, int nbins)
{
    int g = blockIdx.x * 256 + threadIdx.x;
    if (g < nbins) binCursor[g] = g * CAP;

    const int m = blockIdx.x >> 3;
    const int s = (blockIdx.x & 7) * 256 + threadIdx.x;
    const float* W = (m == 0) ? W0 : (m == 1) ? W1 : (m == 2) ? W2 : W3;
    uint4* T = (m == 0) ? T0 : (m == 1) ? T1 : (m == 2) ? T2 : T3;

    const int l = s & 63;
    const int ckk = s >> 6;
    const int kk = ckk & 3;
    const int c = ckk >> 2;
    const int k0 = kk * 32 + (l >> 4) * 8;
    const int col = c * 16 + (l & 15);

    unsigned int b[8];
    #pragma unroll
    for (int j = 0; j < 8; ++j)
        b[j] = f2bf(W[(size_t)(k0 + j) * HD + col]);
    uint4 o;
    o.x = b[0] | (b[1] << 16);
    o.y = b[2] | (b[3] << 16);
    o.z = b[4] | (b[5] << 16);
    o.w = b[6] | (b[7] << 16);
    T[s] = o;
}

// ---------------- dense via MFMA, single-phase, 512 threads ----------------
__global__ __launch_bounds__(512, 4) void gemm_mfma_kernel(
    const float* __restrict__ X,
    const uint4* __restrict__ WlF, const float* __restrict__ bl,
    const uint4* __restrict__ WrF, const float* __restrict__ br,
    unsigned short* __restrict__ Ylb, unsigned short* __restrict__ Yrb, int n)
{
    __shared__ unsigned short xs[64 * HD];   // 16 KB, XOR-swizzled bf16
    __shared__ uint4 bsl[2048];              // 32 KB, fragment-ordered Wl
    __shared__ uint4 bsr[2048];              // 32 KB, fragment-ordered Wr
    const int row0 = blockIdx.x * 64;
    const int tid = threadIdx.x;             // 0..511
    const int lane = tid & 63;
    const int wv = tid >> 6;                 // 0..7

    {
        const float4* Xv = (const float4*)(X + (size_t)row0 * HD);
        #pragma unroll
        for (int i = 0; i < 4; ++i) {
            int idx = tid + i * 512;
            int row = idx >> 5;
            int c4 = idx & 31;
            float4 v = make_float4(0.f, 0.f, 0.f, 0.f);
            if (row0 + row < n) v = Xv[idx];
            ushort4 b;
            b.x = f2bf(v.x); b.y = f2bf(v.y); b.z = f2bf(v.z); b.w = f2bf(v.w);
            int byteoff = row * 256 + ((c4 * 8) ^ ((row & 7) << 4));
            *(ushort4*)((char*)xs + byteoff) = b;
        }
    }
    #pragma unroll
    for (int i = 0; i < 4; ++i) {
        bsl[tid + i * 512] = WlF[tid + i * 512];
        bsr[tid + i * 512] = WrF[tid + i * 512];
    }
    __syncthreads();

    const int r15 = lane & 15;
    const int kg = lane >> 4;
    const int mrow = (wv & 3) * 16 + r15;
    const int cbase = (wv >> 2) * 4;
    const int abase = mrow * 256;
    const int aswz = (mrow & 7) << 4;

    bf16x8 af[4];
    #pragma unroll
    for (int kk = 0; kk < 4; ++kk)
        af[kk] = *(const bf16x8*)((const char*)xs + abase + ((kk * 64 + kg * 16) ^ aswz));

    f32x4 accl[4], accr[4];
    #pragma unroll
    for (int i = 0; i < 4; ++i) {
        accl[i] = (f32x4){0.f, 0.f, 0.f, 0.f};
        accr[i] = (f32x4){0.f, 0.f, 0.f, 0.f};
    }

    #pragma unroll
    for (int kk = 0; kk < 4; ++kk) {
        #pragma unroll
        for (int c = 0; c < 4; ++c) {
            bf16x8 bfl = *(const bf16x8*)&bsl[((cbase + c) * 4 + kk) * 64 + lane];
            accl[c] = __builtin_amdgcn_mfma_f32_16x16x32_bf16(af[kk], bfl, accl[c], 0, 0, 0);
            bf16x8 bfr = *(const bf16x8*)&bsr[((cbase + c) * 4 + kk) * 64 + lane];
            accr[c] = __builtin_amdgcn_mfma_f32_16x16x32_bf16(af[kk], bfr, accr[c], 0, 0, 0);
        }
    }

    const int orow0 = row0 + (wv & 3) * 16 + kg * 4;
    #pragma unroll
    for (int c = 0; c < 4; ++c) {
        const int col = (cbase + c) * 16 + r15;
        const float bLv = bl[col];
        const float bRv = br[col];
        #pragma unroll
        for (int r = 0; r < 4; ++r) {
            int row = orow0 + r;
            if (row < n) {
                Ylb[(size_t)row * HD + col] = f2bf(accl[c][r] + bLv);
                Yrb[(size_t)row * HD + col] = f2bf(accr[c][r] + bRv);
            }
        }
    }
}

// ---------------- CSR build (fixed-capacity bins) ----------------
__global__ __launch_bounds__(256) void bin_scatter_kernel(
    const int* __restrict__ ei, int* __restrict__ binCursor,
    unsigned int* __restrict__ binned, int nE, int nTot, int nbins)
{
    __shared__ int hist[MAXBINS];
    __shared__ int base[MAXBINS];
    for (int i = threadIdx.x; i < nbins; i += 256) hist[i] = 0;
    __syncthreads();
    const int e0 = blockIdx.x * CHUNK;
    const int e1 = min(e0 + CHUNK, nTot);
    for (int e = e0 + threadIdx.x; e < e1; e += 256) {
        int d = (e < nE) ? ei[nE + e] : (e - nE);
        atomicAdd(&hist[d >> 7], 1);
    }
    __syncthreads();
    for (int b = threadIdx.x; b < nbins; b += 256) {
        int c = hist[b];
        base[b] = c ? atomicAdd(&binCursor[b], c) : 0;
        hist[b] = 0;
    }
    __syncthreads();
    for (int e = e0 + threadIdx.x; e < e1; e += 256) {
        int s, d;
        if (e < nE) { s = ei[e]; d = ei[nE + e]; }
        else        { s = e - nE; d = s; }
        int b = d >> 7;
        int r = atomicAdd(&hist[b], 1);
        binned[base[b] + r] = (unsigned int)s | ((unsigned int)(d & (NPB - 1)) << 16);
    }
}

// per-bin fine CSR: padded rows + degree-sorted, block-interleaved pairing
__global__ __launch_bounds__(256) void bin_csr_kernel(
    const int* __restrict__ binCursor, const unsigned int* __restrict__ binned,
    int* __restrict__ rowstart, int* __restrict__ rowlen,
    int* __restrict__ csr_src, int* __restrict__ pairs, int n)
{
    __shared__ int hist[NPB];
    __shared__ int cur[NPB];
    __shared__ int sm[256];
    __shared__ unsigned int srt[NPB];
    const int b = blockIdx.x;
    const int tid = threadIdx.x;
    const int lo = b * CAP;
    const int hi = binCursor[b];

    if (tid < NPB) hist[tid] = 0;
    __syncthreads();
    for (int e = lo + tid; e < hi; e += 256)
        atomicAdd(&hist[(binned[e] >> 16) & (NPB - 1)], 1);
    __syncthreads();
    const int c = (tid < NPB) ? hist[tid] : 0;
    const int rl = (c + 3) & ~3;
    sm[tid] = rl;
    if (tid < NPB) srt[tid] = ((unsigned int)rl << 7) | (unsigned int)tid;
    __syncthreads();
    #pragma unroll
    for (int off = 1; off < 256; off <<= 1) {
        int v = (tid >= off) ? sm[tid - off] : 0;
        __syncthreads();
        sm[tid] += v;
        __syncthreads();
    }
    const int excl = sm[tid] - rl;
    if (tid < NPB) {
        cur[tid] = excl;
        int node = b * NPB + tid;
        if (node < n) { rowstart[node] = lo + excl; rowlen[node] = c; }
    }
    __syncthreads();
    // bitonic sort of (rl, localidx) ascending
    for (int k = 2; k <= NPB; k <<= 1) {
        for (int j = k >> 1; j > 0; j >>= 1) {
            if (tid < NPB) {
                int ixj = tid ^ j;
                if (ixj > tid) {
                    unsigned int a = srt[tid], bb = srt[ixj];
                    bool asc = ((tid & k) == 0);
                    if (asc ? (a > bb) : (a < bb)) { srt[tid] = bb; srt[ixj] = a; }
                }
            }
            __syncthreads();
        }
    }
    // pair j = sorted ranks (2j, 2j+1); scatter pair j to slot t = (j&3)*16 + (j>>2)
    // so each 4-pair block gets widely-separated sorted positions (balanced makespan)
    if (tid < NPB) {
        int j = tid >> 1;
        int pp = tid & 1;
        int t = ((j & 3) << 4) | (j >> 2);
        pairs[b * NPB + 2 * t + pp] = b * NPB + (int)(srt[tid] & 127u);
    }
    // scatter edges
    for (int e = lo + tid; e < hi; e += 256) {
        unsigned int p = binned[e];
        int r = atomicAdd(&cur[(p >> 16) & (NPB - 1)], 1);
        csr_src[lo + r] = (int)(p & 0xFFFFu);
    }
    __syncthreads();
    if (tid < NPB) {
        int node = b * NPB + tid;
        if (node < n) {
            for (int r2 = excl + c; r2 < excl + rl; ++r2) csr_src[lo + r2] = node;
        }
    }
    int total = sm[255];
    if (tid < 64) csr_src[lo + total + tid] = 0;
}

// ---------------- fused GATv2 edge phase ----------------
// 2 balanced dsts/wave (32 lanes x 4 feats), bf16 gathers + bf16 xr, no-max softmax
// with exp2, 8-deep pipeline, PACKED f32x2 math.
__device__ __forceinline__ void gat4(
    uint2 u0, uint2 u1, uint2 u2, uint2 u3,
    const f32x2 xrA, const f32x2 xrB, const f32x2 attA, const f32x2 attB,
    int k0, int len,
    float& den, f32x2& accA, f32x2& accB)
{
    f32x2 c0a = bfpair(u0.x), c0b = bfpair(u0.y);
    f32x2 c1a = bfpair(u1.x), c1b = bfpair(u1.y);
    f32x2 c2a = bfpair(u2.x), c2b = bfpair(u2.y);
    f32x2 c3a = bfpair(u3.x), c3b = bfpair(u3.y);

    f32x2 v, tp;
    float t0, t1, t2, t3;
    v = c0a + xrA; v = __builtin_elementwise_max(v, v * 0.2f); tp = v * attA;
    v = c0b + xrB; v = __builtin_elementwise_max(v, v * 0.2f); tp += v * attB;
    t0 = tp.x + tp.y;
    v = c1a + xrA; v = __builtin_elementwise_max(v, v * 0.2f); tp = v * attA;
    v = c1b + xrB; v = __builtin_elementwise_max(v, v * 0.2f); tp += v * attB;
    t1 = tp.x + tp.y;
    v = c2a + xrA; v = __builtin_elementwise_max(v, v * 0.2f); tp = v * attA;
    v = c2b + xrB; v = __builtin_elementwise_max(v, v * 0.2f); tp += v * attB;
    t2 = tp.x + tp.y;
    v = c3a + xrA; v = __builtin_elementwise_max(v, v * 0.2f); tp = v * attA;
    v = c3b + xrB; v = __builtin_elementwise_max(v, v * 0.2f); tp += v * attB;
    t3 = tp.x + tp.y;

    #pragma unroll
    for (int off = 16; off >= 1; off >>= 1) {
        t0 += __shfl_xor(t0, off);
        t1 += __shfl_xor(t1, off);
        t2 += __shfl_xor(t2, off);
        t3 += __shfl_xor(t3, off);
    }

    if (k0 + 0 >= len) t0 = -1e30f;
    if (k0 + 1 >= len) t1 = -1e30f;
    if (k0 + 2 >= len) t2 = -1e30f;
    if (k0 + 3 >= len) t3 = -1e30f;

    // att pre-scaled by log2(e): exp2(t') == exp(t)
    float p0 = exp2f(t0);
    float p1 = exp2f(t1);
    float p2 = exp2f(t2);
    float p3 = exp2f(t3);
    den += (p0 + p1) + (p2 + p3);
    accA += p0 * c0a + p1 * c1a + p2 * c2a + p3 * c3a;
    accB += p0 * c0b + p1 * c1b + p2 * c2b + p3 * c3b;
}

__global__ __launch_bounds__(256) void fused_gat_kernel(
    const int* __restrict__ pairs,
    const int* __restrict__ rowstart, const int* __restrict__ rowlen,
    const int* __restrict__ csr_src,
    const unsigned short* __restrict__ xlb, const unsigned short* __restrict__ xrb,
    const float* __restrict__ att, const float* __restrict__ bias,
    float* __restrict__ out, int n, int doAct)
{
    const int wid  = blockIdx.x * 4 + (threadIdx.x >> 6);
    const int lane = threadIdx.x & 63;
    const int dp   = wid * 2 + (lane >> 5);
    const int d    = pairs[dp];
    const int fl   = (lane & 31) * 4;

    const float LOG2E = 1.44269504088896f;
    const float4 attf = *(const float4*)(att + fl);
    const f32x2 attA = (f32x2){attf.x * LOG2E, attf.y * LOG2E};
    const f32x2 attB = (f32x2){attf.z * LOG2E, attf.w * LOG2E};

    f32x2 xrA = (f32x2){0.f, 0.f}, xrB = (f32x2){0.f, 0.f};
    int rp = 0, len = 0;
    if (d < n) {
        uint2 xru = *(const uint2*)(xrb + (size_t)d * HD + fl);
        xrA = bfpair(xru.x);
        xrB = bfpair(xru.y);
        rp  = rowstart[d];
        len = rowlen[d];
    }
    const int rl = (len + 3) & ~3;
    const int ml = max(rl, __shfl_xor(rl, 32));   // shared trip count, multiple of 4

    float den = 0.f;
    f32x2 accA = (f32x2){0.f, 0.f}, accB = (f32x2){0.f, 0.f};

    const unsigned short* xfl = xlb + fl;

    // prologue: 8 edges in flight
    uint2 a0, a1, a2, a3, b0, b1, b2, b3;
    {
        int i0 = csr_src[rp + 0], i1 = csr_src[rp + 1];
        int i2 = csr_src[rp + 2], i3 = csr_src[rp + 3];
        int j0 = csr_src[rp + 4], j1 = csr_src[rp + 5];
        int j2 = csr_src[rp + 6], j3 = csr_src[rp + 7];
        a0 = *(const uint2*)(xfl + (size_t)i0 * HD);
        a1 = *(const uint2*)(xfl + (size_t)i1 * HD);
        a2 = *(const uint2*)(xfl + (size_t)i2 * HD);
        a3 = *(const uint2*)(xfl + (size_t)i3 * HD);
        b0 = *(const uint2*)(xfl + (size_t)j0 * HD);
        b1 = *(const uint2*)(xfl + (size_t)j1 * HD);
        b2 = *(const uint2*)(xfl + (size_t)j2 * HD);
        b3 = *(const uint2*)(xfl + (size_t)j3 * HD);
    }

    for (int k0 = 0; k0 < ml; k0 += 8) {
        uint2 u0 = a0, u1 = a1, u2 = a2, u3 = a3;
        int kn = k0 + 8;
        if (kn < ml) {
            int i0 = csr_src[rp + kn + 0], i1 = csr_src[rp + kn + 1];
            int i2 = csr_src[rp + kn + 2], i3 = csr_src[rp + kn + 3];
            a0 = *(const uint2*)(xfl + (size_t)i0 * HD);
            a1 = *(const uint2*)(xfl + (size_t)i1 * HD);
            a2 = *(const uint2*)(xfl + (size_t)i2 * HD);
            a3 = *(const uint2*)(xfl + (size_t)i3 * HD);
        }
        gat4(u0, u1, u2, u3, xrA, xrB, attA, attB, k0, len, den, accA, accB);

        if (k0 + 4 < ml) {
            uint2 v0 = b0, v1 = b1, v2 = b2, v3 = b3;
            int km = k0 + 12;
            if (km < ml) {
                int j0 = csr_src[rp + km + 0], j1 = csr_src[rp + km + 1];
                int j2 = csr_src[rp + km + 2], j3 = csr_src[rp + km + 3];
                b0 = *(const uint2*)(xfl + (size_t)j0 * HD);
                b1 = *(const uint2*)(xfl + (size_t)j1 * HD);
                b2 = *(const uint2*)(xfl + (size_t)j2 * HD);
                b3 = *(const uint2*)(xfl + (size_t)j3 * HD);
            }
            gat4(v0, v1, v2, v3, xrA, xrB, attA, attB, k0 + 4, len, den, accA, accB);
        }
    }

    if (d < n) {
        const float4 bv = *(const float4*)(bias + fl);
        float inv = 1.f / den;
        float o0 = accA.x * inv + bv.x;
        float o1 = accA.y * inv + bv.y;
        float o2 = accB.x * inv + bv.z;
        float o3 = accB.y * inv + bv.w;
        if (doAct) {
            o0 = (o0 > 0.f) ? o0 : 0.01f * o0;
            o1 = (o1 > 0.f) ? o1 : 0.01f * o1;
            o2 = (o2 > 0.f) ? o2 : 0.01f * o2;
            o3 = (o3 > 0.f) ? o3 : 0.01f * o3;
        }
        *(float4*)(out + (size_t)d * HD + fl) = make_float4(o0, o1, o2, o3);
    }
}

extern "C" void kernel_launch(void* const* d_in, const int* in_sizes, int n_in,
                              void* d_out, int out_size, void* d_ws, size_t ws_size,
                              hipStream_t stream)
{
    const float* x    = (const float*)d_in[0];
    const int*   ei   = (const int*)d_in[1];
    const float* Wl1  = (const float*)d_in[2];
    const float* bl1  = (const float*)d_in[3];
    const float* Wr1  = (const float*)d_in[4];
    const float* br1  = (const float*)d_in[5];
    const float* att1 = (const float*)d_in[6];
    const float* b1   = (const float*)d_in[7];
    const float* Wl2  = (const float*)d_in[8];
    const float* bl2  = (const float*)d_in[9];
    const float* Wr2  = (const float*)d_in[10];
    const float* br2  = (const float*)d_in[11];
    const float* att2 = (const float*)d_in[12];
    const float* b2   = (const float*)d_in[13];

    const int n    = in_sizes[0] / HD;
    const int E    = in_sizes[1] / 2;
    const int nTot = E + n;
    const int nbins = (n + NPB - 1) / NPB;
    const int np   = nbins * NPB;

    char* ws = (char*)d_ws;
    const size_t feat_bytes = (size_t)n * HD * sizeof(float);
    const size_t bf_bytes   = ((size_t)n * HD * 2 + 511) & ~(size_t)511;
    const size_t wt_bytes   = ((size_t)HD * HD * 2 + 511) & ~(size_t)511;
    auto alignup = [](size_t v) { return (v + 511) & ~(size_t)511; };
    unsigned short* xlb = (unsigned short*)ws; ws += bf_bytes;
    unsigned short* xrb = (unsigned short*)ws; ws += bf_bytes;
    float* h  = (float*)ws;          ws += feat_bytes;
    uint4* wlF1 = (uint4*)ws; ws += wt_bytes;
    uint4* wrF1 = (uint4*)ws; ws += wt_bytes;
    uint4* wlF2 = (uint4*)ws; ws += wt_bytes;
    uint4* wrF2 = (uint4*)ws; ws += wt_bytes;
    int* binCursor = (int*)ws;       ws += alignup((size_t)nbins * 4);
    int* rowstart  = (int*)ws;       ws += alignup((size_t)n * 4);
    int* rowlen    = (int*)ws;       ws += alignup((size_t)n * 4);
    int* pairs     = (int*)ws;       ws += alignup((size_t)np * 4);
    unsigned int* binned = (unsigned int*)ws; ws += alignup((size_t)nbins * CAP * 4);
    int* csr_src   = (int*)ws;       ws += alignup((size_t)nbins * CAP * 4);

    float* out = (float*)d_out;

    const int nChunk = (nTot + CHUNK - 1) / CHUNK;
    dim3 gb(512); dim3 gg((n + 63) / 64);
    dim3 fb(256); dim3 fg((np + 7) / 8);

    // ---------------- W prep (+cursor init) + CSR build ----------------
    wprep_kernel<<<32, 256, 0, stream>>>(Wl1, Wr1, Wl2, Wr2, wlF1, wrF1, wlF2, wrF2,
                                         binCursor, nbins);
    bin_scatter_kernel<<<nChunk, 256, 0, stream>>>(ei, binCursor, binned, E, nTot, nbins);
    bin_csr_kernel<<<nbins, 256, 0, stream>>>(binCursor, binned, rowstart, rowlen, csr_src, pairs, n);

    // ---------------- layer 1 ----------------
    gemm_mfma_kernel<<<gg, gb, 0, stream>>>(x, wlF1, bl1, wrF1, br1, xlb, xrb, n);
    fused_gat_kernel<<<fg, fb, 0, stream>>>(pairs, rowstart, rowlen, csr_src, xlb, xrb, att1, b1, h, n, 1);

    // ---------------- layer 2 ----------------
    gemm_mfma_kernel<<<gg, gb, 0, stream>>>(h, wlF2, bl2, wrF2, br2, xlb, xrb, n);
    fused_gat_kernel<<<fg, fb, 0, stream>>>(pairs, rowstart, rowlen, csr_src, xlb, xrb, att2, b2, out, n, 0);
}

// Round 18
// 158.541 us; speedup vs baseline: 1.0900x; 1.0900x over previous
//
#include <hip/hip_runtime.h>
#include <math.h>

#define HD 128
#define CHUNK 2048   // edges per binning block
#define MAXBINS 512
#define NPB 128      // nodes per bin
#define CAP 3072     // per-bin capacity (mean 2176, +19 sigma)

typedef __attribute__((ext_vector_type(8))) short bf16x8;
typedef __attribute__((ext_vector_type(4))) float f32x4;
typedef __attribute__((ext_vector_type(2))) float f32x2;

// RNE float -> bf16
__device__ __forceinline__ unsigned short f2bf(float f) {
    unsigned int u = __float_as_uint(f);
    u += 0x7FFFu + ((u >> 16) & 1u);
    return (unsigned short)(u >> 16);
}
// packed bf16 pair -> f32x2
__device__ __forceinline__ f32x2 bfpair(unsigned int p) {
    f32x2 r;
    r.x = __uint_as_float(p << 16);
    r.y = __uint_as_float(p & 0xFFFF0000u);
    return r;
}

// ---------------- W prep: fragment-ordered bf16 B operands (+ cursor init) ----------------
__global__ __launch_bounds__(256) void wprep_kernel(
    const float* __restrict__ W0, const float* __restrict__ W1,
    const float* __restrict__ W2, const float* __restrict__ W3,
    uint4* __restrict__ T0, uint4* __restrict__ T1,
    uint4* __restrict__ T2, uint4* __restrict__ T3,
    int* __restrict__ binCursor, int nbins)
{
    int g = blockIdx.x * 256 + threadIdx.x;
    if (g < nbins) binCursor[g] = g * CAP;

    const int m = blockIdx.x >> 3;
    const int s = (blockIdx.x & 7) * 256 + threadIdx.x;
    const float* W = (m == 0) ? W0 : (m == 1) ? W1 : (m == 2) ? W2 : W3;
    uint4* T = (m == 0) ? T0 : (m == 1) ? T1 : (m == 2) ? T2 : T3;

    const int l = s & 63;
    const int ckk = s >> 6;
    const int kk = ckk & 3;
    const int c = ckk >> 2;
    const int k0 = kk * 32 + (l >> 4) * 8;
    const int col = c * 16 + (l & 15);

    unsigned int b[8];
    #pragma unroll
    for (int j = 0; j < 8; ++j)
        b[j] = f2bf(W[(size_t)(k0 + j) * HD + col]);
    uint4 o;
    o.x = b[0] | (b[1] << 16);
    o.y = b[2] | (b[3] << 16);
    o.z = b[4] | (b[5] << 16);
    o.w = b[6] | (b[7] << 16);
    T[s] = o;
}

// ---------------- dense via MFMA, single-phase, 512 threads ----------------
__global__ __launch_bounds__(512, 4) void gemm_mfma_kernel(
    const float* __restrict__ X,
    const uint4* __restrict__ WlF, const float* __restrict__ bl,
    const uint4* __restrict__ WrF, const float* __restrict__ br,
    unsigned short* __restrict__ Ylb, unsigned short* __restrict__ Yrb, int n)
{
    __shared__ unsigned short xs[64 * HD];   // 16 KB, XOR-swizzled bf16
    __shared__ uint4 bsl[2048];              // 32 KB, fragment-ordered Wl
    __shared__ uint4 bsr[2048];              // 32 KB, fragment-ordered Wr
    const int row0 = blockIdx.x * 64;
    const int tid = threadIdx.x;             // 0..511
    const int lane = tid & 63;
    const int wv = tid >> 6;                 // 0..7

    {
        const float4* Xv = (const float4*)(X + (size_t)row0 * HD);
        #pragma unroll
        for (int i = 0; i < 4; ++i) {
            int idx = tid + i * 512;
            int row = idx >> 5;
            int c4 = idx & 31;
            float4 v = make_float4(0.f, 0.f, 0.f, 0.f);
            if (row0 + row < n) v = Xv[idx];
            ushort4 b;
            b.x = f2bf(v.x); b.y = f2bf(v.y); b.z = f2bf(v.z); b.w = f2bf(v.w);
            int byteoff = row * 256 + ((c4 * 8) ^ ((row & 7) << 4));
            *(ushort4*)((char*)xs + byteoff) = b;
        }
    }
    #pragma unroll
    for (int i = 0; i < 4; ++i) {
        bsl[tid + i * 512] = WlF[tid + i * 512];
        bsr[tid + i * 512] = WrF[tid + i * 512];
    }
    __syncthreads();

    const int r15 = lane & 15;
    const int kg = lane >> 4;
    const int mrow = (wv & 3) * 16 + r15;
    const int cbase = (wv >> 2) * 4;
    const int abase = mrow * 256;
    const int aswz = (mrow & 7) << 4;

    bf16x8 af[4];
    #pragma unroll
    for (int kk = 0; kk < 4; ++kk)
        af[kk] = *(const bf16x8*)((const char*)xs + abase + ((kk * 64 + kg * 16) ^ aswz));

    f32x4 accl[4], accr[4];
    #pragma unroll
    for (int i = 0; i < 4; ++i) {
        accl[i] = (f32x4){0.f, 0.f, 0.f, 0.f};
        accr[i] = (f32x4){0.f, 0.f, 0.f, 0.f};
    }

    #pragma unroll
    for (int kk = 0; kk < 4; ++kk) {
        #pragma unroll
        for (int c = 0; c < 4; ++c) {
            bf16x8 bfl = *(const bf16x8*)&bsl[((cbase + c) * 4 + kk) * 64 + lane];
            accl[c] = __builtin_amdgcn_mfma_f32_16x16x32_bf16(af[kk], bfl, accl[c], 0, 0, 0);
            bf16x8 bfr = *(const bf16x8*)&bsr[((cbase + c) * 4 + kk) * 64 + lane];
            accr[c] = __builtin_amdgcn_mfma_f32_16x16x32_bf16(af[kk], bfr, accr[c], 0, 0, 0);
        }
    }

    const int orow0 = row0 + (wv & 3) * 16 + kg * 4;
    #pragma unroll
    for (int c = 0; c < 4; ++c) {
        const int col = (cbase + c) * 16 + r15;
        const float bLv = bl[col];
        const float bRv = br[col];
        #pragma unroll
        for (int r = 0; r < 4; ++r) {
            int row = orow0 + r;
            if (row < n) {
                Ylb[(size_t)row * HD + col] = f2bf(accl[c][r] + bLv);
                Yrb[(size_t)row * HD + col] = f2bf(accr[c][r] + bRv);
            }
        }
    }
}

// ---------------- CSR build (fixed-capacity bins) ----------------
__global__ __launch_bounds__(256) void bin_scatter_kernel(
    const int* __restrict__ ei, int* __restrict__ binCursor,
    unsigned int* __restrict__ binned, int nE, int nTot, int nbins)
{
    __shared__ int hist[MAXBINS];
    __shared__ int base[MAXBINS];
    for (int i = threadIdx.x; i < nbins; i += 256) hist[i] = 0;
    __syncthreads();
    const int e0 = blockIdx.x * CHUNK;
    const int e1 = min(e0 + CHUNK, nTot);
    for (int e = e0 + threadIdx.x; e < e1; e += 256) {
        int d = (e < nE) ? ei[nE + e] : (e - nE);
        atomicAdd(&hist[d >> 7], 1);
    }
    __syncthreads();
    for (int b = threadIdx.x; b < nbins; b += 256) {
        int c = hist[b];
        base[b] = c ? atomicAdd(&binCursor[b], c) : 0;
        hist[b] = 0;
    }
    __syncthreads();
    for (int e = e0 + threadIdx.x; e < e1; e += 256) {
        int s, d;
        if (e < nE) { s = ei[e]; d = ei[nE + e]; }
        else        { s = e - nE; d = s; }
        int b = d >> 7;
        int r = atomicAdd(&hist[b], 1);
        binned[base[b] + r] = (unsigned int)s | ((unsigned int)(d & (NPB - 1)) << 16);
    }
}

__global__ __launch_bounds__(256) void bin_csr_kernel(
    const int* __restrict__ binCursor, const unsigned int* __restrict__ binned,
    int* __restrict__ rowstart, int* __restrict__ rowlen,
    int* __restrict__ csr_src, int n)
{
    __shared__ int hist[NPB];
    __shared__ int cur[NPB];
    __shared__ int sm[256];
    const int b = blockIdx.x;
    const int tid = threadIdx.x;
    const int lo = b * CAP;
    const int hi = binCursor[b];

    if (tid < NPB) hist[tid] = 0;
    __syncthreads();
    for (int e = lo + tid; e < hi; e += 256)
        atomicAdd(&hist[(binned[e] >> 16) & (NPB - 1)], 1);
    __syncthreads();
    const int c = (tid < NPB) ? hist[tid] : 0;
    const int rl = (c + 3) & ~3;
    sm[tid] = rl;
    __syncthreads();
    #pragma unroll
    for (int off = 1; off < 256; off <<= 1) {
        int v = (tid >= off) ? sm[tid - off] : 0;
        __syncthreads();
        sm[tid] += v;
        __syncthreads();
    }
    const int excl = sm[tid] - rl;
    if (tid < NPB) {
        cur[tid] = excl;
        int node = b * NPB + tid;
        if (node < n) { rowstart[node] = lo + excl; rowlen[node] = c; }
    }
    __syncthreads();
    for (int e = lo + tid; e < hi; e += 256) {
        unsigned int p = binned[e];
        int r = atomicAdd(&cur[(p >> 16) & (NPB - 1)], 1);
        csr_src[lo + r] = (int)(p & 0xFFFFu);
    }
    __syncthreads();
    if (tid < NPB) {
        int node = b * NPB + tid;
        if (node < n) {
            for (int r2 = excl + c; r2 < excl + rl; ++r2) csr_src[lo + r2] = node;
        }
    }
    int total = sm[255];
    if (tid < 64) csr_src[lo + total + tid] = 0;
}

// ---------------- fused GATv2 edge phase ----------------
// 2 dsts/wave (32 lanes x 4 feats), bf16 gathers + bf16 xr, no-max softmax with exp2,
// 8-deep pipeline, PACKED f32x2 math (v_pk_* dual-issue).
__device__ __forceinline__ void gat4(
    uint2 u0, uint2 u1, uint2 u2, uint2 u3,
    const f32x2 xrA, const f32x2 xrB, const f32x2 attA, const f32x2 attB,
    int k0, int len,
    float& den, f32x2& accA, f32x2& accB)
{
    f32x2 c0a = bfpair(u0.x), c0b = bfpair(u0.y);
    f32x2 c1a = bfpair(u1.x), c1b = bfpair(u1.y);
    f32x2 c2a = bfpair(u2.x), c2b = bfpair(u2.y);
    f32x2 c3a = bfpair(u3.x), c3b = bfpair(u3.y);

    f32x2 v, tp;
    float t0, t1, t2, t3;
    v = c0a + xrA; v = __builtin_elementwise_max(v, v * 0.2f); tp = v * attA;
    v = c0b + xrB; v = __builtin_elementwise_max(v, v * 0.2f); tp += v * attB;
    t0 = tp.x + tp.y;
    v = c1a + xrA; v = __builtin_elementwise_max(v, v * 0.2f); tp = v * attA;
    v = c1b + xrB; v = __builtin_elementwise_max(v, v * 0.2f); tp += v * attB;
    t1 = tp.x + tp.y;
    v = c2a + xrA; v = __builtin_elementwise_max(v, v * 0.2f); tp = v * attA;
    v = c2b + xrB; v = __builtin_elementwise_max(v, v * 0.2f); tp += v * attB;
    t2 = tp.x + tp.y;
    v = c3a + xrA; v = __builtin_elementwise_max(v, v * 0.2f); tp = v * attA;
    v = c3b + xrB; v = __builtin_elementwise_max(v, v * 0.2f); tp += v * attB;
    t3 = tp.x + tp.y;

    #pragma unroll
    for (int off = 16; off >= 1; off >>= 1) {
        t0 += __shfl_xor(t0, off);
        t1 += __shfl_xor(t1, off);
        t2 += __shfl_xor(t2, off);
        t3 += __shfl_xor(t3, off);
    }

    if (k0 + 0 >= len) t0 = -1e30f;
    if (k0 + 1 >= len) t1 = -1e30f;
    if (k0 + 2 >= len) t2 = -1e30f;
    if (k0 + 3 >= len) t3 = -1e30f;

    // att pre-scaled by log2(e): exp2(t') == exp(t)
    float p0 = exp2f(t0);
    float p1 = exp2f(t1);
    float p2 = exp2f(t2);
    float p3 = exp2f(t3);
    den += (p0 + p1) + (p2 + p3);
    accA += p0 * c0a + p1 * c1a + p2 * c2a + p3 * c3a;
    accB += p0 * c0b + p1 * c1b + p2 * c2b + p3 * c3b;
}

__global__ __launch_bounds__(256) void fused_gat_kernel(
    const int* __restrict__ rowstart, const int* __restrict__ rowlen,
    const int* __restrict__ csr_src,
    const unsigned short* __restrict__ xlb, const unsigned short* __restrict__ xrb,
    const float* __restrict__ att, const float* __restrict__ bias,
    float* __restrict__ out, int n, int doAct)
{
    const int wid  = blockIdx.x * 4 + (threadIdx.x >> 6);
    const int lane = threadIdx.x & 63;
    const int d    = wid * 2 + (lane >> 5);
    const int fl   = (lane & 31) * 4;

    const float LOG2E = 1.44269504088896f;
    const float4 attf = *(const float4*)(att + fl);
    const f32x2 attA = (f32x2){attf.x * LOG2E, attf.y * LOG2E};
    const f32x2 attB = (f32x2){attf.z * LOG2E, attf.w * LOG2E};

    f32x2 xrA = (f32x2){0.f, 0.f}, xrB = (f32x2){0.f, 0.f};
    int rp = 0, len = 0;
    if (d < n) {
        uint2 xru = *(const uint2*)(xrb + (size_t)d * HD + fl);
        xrA = bfpair(xru.x);
        xrB = bfpair(xru.y);
        rp  = rowstart[d];
        len = rowlen[d];
    }
    const int rl = (len + 3) & ~3;
    const int ml = max(rl, __shfl_xor(rl, 32));   // shared trip count, multiple of 4

    float den = 0.f;
    f32x2 accA = (f32x2){0.f, 0.f}, accB = (f32x2){0.f, 0.f};

    const unsigned short* xfl = xlb + fl;

    // prologue: 8 edges in flight
    uint2 a0, a1, a2, a3, b0, b1, b2, b3;
    {
        int i0 = csr_src[rp + 0], i1 = csr_src[rp + 1];
        int i2 = csr_src[rp + 2], i3 = csr_src[rp + 3];
        int j0 = csr_src[rp + 4], j1 = csr_src[rp + 5];
        int j2 = csr_src[rp + 6], j3 = csr_src[rp + 7];
        a0 = *(const uint2*)(xfl + (size_t)i0 * HD);
        a1 = *(const uint2*)(xfl + (size_t)i1 * HD);
        a2 = *(const uint2*)(xfl + (size_t)i2 * HD);
        a3 = *(const uint2*)(xfl + (size_t)i3 * HD);
        b0 = *(const uint2*)(xfl + (size_t)j0 * HD);
        b1 = *(const uint2*)(xfl + (size_t)j1 * HD);
        b2 = *(const uint2*)(xfl + (size_t)j2 * HD);
        b3 = *(const uint2*)(xfl + (size_t)j3 * HD);
    }

    for (int k0 = 0; k0 < ml; k0 += 8) {
        uint2 u0 = a0, u1 = a1, u2 = a2, u3 = a3;
        int kn = k0 + 8;
        if (kn < ml) {
            int i0 = csr_src[rp + kn + 0], i1 = csr_src[rp + kn + 1];
            int i2 = csr_src[rp + kn + 2], i3 = csr_src[rp + kn + 3];
            a0 = *(const uint2*)(xfl + (size_t)i0 * HD);
            a1 = *(const uint2*)(xfl + (size_t)i1 * HD);
            a2 = *(const uint2*)(xfl + (size_t)i2 * HD);
            a3 = *(const uint2*)(xfl + (size_t)i3 * HD);
        }
        gat4(u0, u1, u2, u3, xrA, xrB, attA, attB, k0, len, den, accA, accB);

        if (k0 + 4 < ml) {
            uint2 v0 = b0, v1 = b1, v2 = b2, v3 = b3;
            int km = k0 + 12;
            if (km < ml) {
                int j0 = csr_src[rp + km + 0], j1 = csr_src[rp + km + 1];
                int j2 = csr_src[rp + km + 2], j3 = csr_src[rp + km + 3];
                b0 = *(const uint2*)(xfl + (size_t)j0 * HD);
                b1 = *(const uint2*)(xfl + (size_t)j1 * HD);
                b2 = *(const uint2*)(xfl + (size_t)j2 * HD);
                b3 = *(const uint2*)(xfl + (size_t)j3 * HD);
            }
            gat4(v0, v1, v2, v3, xrA, xrB, attA, attB, k0 + 4, len, den, accA, accB);
        }
    }

    if (d < n) {
        const float4 bv = *(const float4*)(bias + fl);
        float inv = 1.f / den;
        float o0 = accA.x * inv + bv.x;
        float o1 = accA.y * inv + bv.y;
        float o2 = accB.x * inv + bv.z;
        float o3 = accB.y * inv + bv.w;
        if (doAct) {
            o0 = (o0 > 0.f) ? o0 : 0.01f * o0;
            o1 = (o1 > 0.f) ? o1 : 0.01f * o1;
            o2 = (o2 > 0.f) ? o2 : 0.01f * o2;
            o3 = (o3 > 0.f) ? o3 : 0.01f * o3;
        }
        *(float4*)(out + (size_t)d * HD + fl) = make_float4(o0, o1, o2, o3);
    }
}

extern "C" void kernel_launch(void* const* d_in, const int* in_sizes, int n_in,
                              void* d_out, int out_size, void* d_ws, size_t ws_size,
                              hipStream_t stream)
{
    const float* x    = (const float*)d_in[0];
    const int*   ei   = (const int*)d_in[1];
    const float* Wl1  = (const float*)d_in[2];
    const float* bl1  = (const float*)d_in[3];
    const float* Wr1  = (const float*)d_in[4];
    const float* br1  = (const float*)d_in[5];
    const float* att1 = (const float*)d_in[6];
    const float* b1   = (const float*)d_in[7];
    const float* Wl2  = (const float*)d_in[8];
    const float* bl2  = (const float*)d_in[9];
    const float* Wr2  = (const float*)d_in[10];
    const float* br2  = (const float*)d_in[11];
    const float* att2 = (const float*)d_in[12];
    const float* b2   = (const float*)d_in[13];

    const int n    = in_sizes[0] / HD;
    const int E    = in_sizes[1] / 2;
    const int nTot = E + n;
    const int nbins = (n + NPB - 1) / NPB;

    char* ws = (char*)d_ws;
    const size_t feat_bytes = (size_t)n * HD * sizeof(float);
    const size_t bf_bytes   = ((size_t)n * HD * 2 + 511) & ~(size_t)511;
    const size_t wt_bytes   = ((size_t)HD * HD * 2 + 511) & ~(size_t)511;
    auto alignup = [](size_t v) { return (v + 511) & ~(size_t)511; };
    unsigned short* xlb = (unsigned short*)ws; ws += bf_bytes;
    unsigned short* xrb = (unsigned short*)ws; ws += bf_bytes;
    float* h  = (float*)ws;          ws += feat_bytes;
    uint4* wlF1 = (uint4*)ws; ws += wt_bytes;
    uint4* wrF1 = (uint4*)ws; ws += wt_bytes;
    uint4* wlF2 = (uint4*)ws; ws += wt_bytes;
    uint4* wrF2 = (uint4*)ws; ws += wt_bytes;
    int* binCursor = (int*)ws;       ws += alignup((size_t)nbins * 4);
    int* rowstart  = (int*)ws;       ws += alignup((size_t)n * 4);
    int* rowlen    = (int*)ws;       ws += alignup((size_t)n * 4);
    unsigned int* binned = (unsigned int*)ws; ws += alignup((size_t)nbins * CAP * 4);
    int* csr_src   = (int*)ws;       ws += alignup((size_t)nbins * CAP * 4);

    float* out = (float*)d_out;

    const int nChunk = (nTot + CHUNK - 1) / CHUNK;
    dim3 gb(512); dim3 gg((n + 63) / 64);
    dim3 fb(256); dim3 fg((n + 7) / 8);

    // ---------------- W prep (+cursor init) + CSR build ----------------
    wprep_kernel<<<32, 256, 0, stream>>>(Wl1, Wr1, Wl2, Wr2, wlF1, wrF1, wlF2, wrF2,
                                         binCursor, nbins);
    bin_scatter_kernel<<<nChunk, 256, 0, stream>>>(ei, binCursor, binned, E, nTot, nbins);
    bin_csr_kernel<<<nbins, 256, 0, stream>>>(binCursor, binned, rowstart, rowlen, csr_src, n);

    // ---------------- layer 1 ----------------
    gemm_mfma_kernel<<<gg, gb, 0, stream>>>(x, wlF1, bl1, wrF1, br1, xlb, xrb, n);
    fused_gat_kernel<<<fg, fb, 0, stream>>>(rowstart, rowlen, csr_src, xlb, xrb, att1, b1, h, n, 1);

    // ---------------- layer 2 ----------------
    gemm_mfma_kernel<<<gg, gb, 0, stream>>>(h, wlF2, bl2, wrF2, br2, xlb, xrb, n);
    fused_gat_kernel<<<fg, fb, 0, stream>>>(rowstart, rowlen, csr_src, xlb, xrb, att2, b2, out, n, 0);
}